// Round 13
// baseline (190.864 us; speedup 1.0000x reference)
//
#include <hip/hip_runtime.h>

using f32x4 = __attribute__((ext_vector_type(4))) float;

constexpr int   N = 8192;
constexpr int   D = 512;
// sqrt((1/T) * log2(e)) folded into the normalized vectors; dot feeds exp2 directly.
constexpr float SCALE_FOLD = 1.6986436f;
constexpr int   CGROUPS = 64;                        // 64 col groups of 128

static __device__ __forceinline__ void gld16(const unsigned char* g, unsigned char* l) {
  __builtin_amdgcn_global_load_lds(
      (const __attribute__((address_space(1))) void*)g,
      (__attribute__((address_space(3))) void*)l, 16, 0, 0);
}

// One wave per row; rows [0,N) -> out0, [N,2N) -> out1.  f32 -> fp8 e4m3 (OCP).
__global__ __launch_bounds__(256) void normalize_kernel(
    const float* __restrict__ in0, const float* __restrict__ in1,
    unsigned char* __restrict__ n0, unsigned char* __restrict__ n1) {
  int gw   = (blockIdx.x * 256 + threadIdx.x) >> 6;
  int lane = threadIdx.x & 63;
  const float* src = (gw < N) ? in0 + (size_t)gw * D : in1 + (size_t)(gw - N) * D;
  unsigned char* dst = ((gw < N) ? n0 + (size_t)gw * D : n1 + (size_t)(gw - N) * D) + lane * 8;

  const float4* s4 = reinterpret_cast<const float4*>(src) + (size_t)lane * 2;
  float4 v0 = s4[0], v1 = s4[1];
  float ss = v0.x*v0.x + v0.y*v0.y + v0.z*v0.z + v0.w*v0.w
           + v1.x*v1.x + v1.y*v1.y + v1.z*v1.z + v1.w*v1.w;
#pragma unroll
  for (int m = 1; m <= 32; m <<= 1) ss += __shfl_xor(ss, m);
  float s = SCALE_FOLD / fmaxf(sqrtf(ss), 1e-12f);

  int w0 = 0, w1 = 0;
  w0 = __builtin_amdgcn_cvt_pk_fp8_f32(v0.x * s, v0.y * s, w0, false);
  w0 = __builtin_amdgcn_cvt_pk_fp8_f32(v0.z * s, v0.w * s, w0, true);
  w1 = __builtin_amdgcn_cvt_pk_fp8_f32(v1.x * s, v1.y * s, w1, false);
  w1 = __builtin_amdgcn_cvt_pk_fp8_f32(v1.z * s, v1.w * s, w1, true);
  int2 o; o.x = w0; o.y = w1;
  *reinterpret_cast<int2*>(dst) = o;
}

// fp8 fused GEMM: 128x128 tile, 4 waves, BK=64 (8 K-steps), 3-deep circular LDS
// (48 KiB), counted vmcnt(4) gates. Per step: 8 b64-pair LDS reads vs 32 MFMA.
// Row stride 64 B -> 2-way bank aliasing (free), no swizzle, linear gld16 dest.
__global__ __launch_bounds__(256) void ntxent_main(
    const unsigned char* __restrict__ n0, const unsigned char* __restrict__ n1,
    const int* __restrict__ labels,
    float* __restrict__ part_pos, float* __restrict__ part_all) {
  __shared__ unsigned char As[3][128 * 64];   // 24 KiB
  __shared__ unsigned char Bs[3][128 * 64];   // 24 KiB
  __shared__ float redS[256];                 // 1 KiB
  __shared__ int   labL[128];                 // 0.5 KiB

  const int t    = threadIdx.x;
  const int lane = t & 63;
  const int wid  = t >> 6;
  const int lr   = lane & 15;
  const int lhi  = lane >> 4;
  const int wr   = wid >> 1;   // 0/1 : rows wr*64..+64
  const int wc   = wid & 1;    // 0/1 : cols wc*64..+64

  // Bijective XCD swizzle (grid = 4096, %8==0)
  const int swz = (blockIdx.x & 7) * 512 + (blockIdx.x >> 3);
  const int rowtile = swz >> 6;        // 0..63
  const int colgrp  = swz & 63;        // 0..63
  const int rowbase = rowtile * 128;
  const int colb    = colgrp * 128;

  if (t < 128) labL[t] = labels[rowbase + t];

  // ---- staging (linear; sweep = 256 thr x 16B = 64 rows x 64B) ----
  const unsigned char* gA = n0 + (size_t)(rowbase + (t >> 2)) * D + (t & 3) * 16;
  const unsigned char* gB = n1 + (size_t)(colb    + (t >> 2)) * D + (t & 3) * 16;
  unsigned char* const lA = &As[0][0] + (t >> 2) * 64 + (t & 3) * 16;
  unsigned char* const lB = &Bs[0][0] + (t >> 2) * 64 + (t & 3) * 16;

#define STAGE(st, sb) do { \
    const unsigned char* _ga = gA + (st) * 64; \
    const unsigned char* _gb = gB + (st) * 64; \
    unsigned char* _la = lA + (sb) * 8192; \
    unsigned char* _lb = lB + (sb) * 8192; \
    gld16(_ga, _la); gld16(_ga + (size_t)64 * D, _la + 4096); \
    gld16(_gb, _lb); gld16(_gb + (size_t)64 * D, _lb + 4096); \
  } while (0)

  // ---- ds_read byte offsets (no swizzle; 2-way free) ----
  int aoff[4];
#pragma unroll
  for (int m = 0; m < 4; ++m) aoff[m] = (wr * 64 + m * 16 + lr) * 64 + lhi * 8;
  int boff[4];
#pragma unroll
  for (int j = 0; j < 4; ++j) boff[j] = (wc * 64 + j * 16 + lr) * 64 + lhi * 8;

#define GATE4 asm volatile("s_waitcnt vmcnt(4)\n\ts_barrier" ::: "memory")
#define GATE0 asm volatile("s_waitcnt vmcnt(0)\n\ts_barrier" ::: "memory")
#define EBAR  asm volatile("s_waitcnt lgkmcnt(0)\n\ts_barrier" ::: "memory")

  f32x4 acc[4][4];
#pragma unroll
  for (int m = 0; m < 4; ++m)
#pragma unroll
    for (int j = 0; j < 4; ++j) acc[m][j] = (f32x4){0.f, 0.f, 0.f, 0.f};

  // prologue: stage k-tiles 0,1 into bufs 0,1  (8 loads outstanding)
  STAGE(0, 0);
  STAGE(1, 1);

#pragma unroll
  for (int kk = 0; kk < 8; ++kk) {
    // drain own oldest k-tile's 4 loads; keep next tile's 4 in flight
    if (kk < 7) { GATE4; } else { GATE0; }

    // stage k-tile kk+2 into buf (kk+2)%3 (readers finished at step kk-1)
    if (kk < 6) STAGE(kk + 2, (kk + 2) % 3);

    const unsigned char* bufA = &As[kk % 3][0];
    const unsigned char* bufB = &Bs[kk % 3][0];
    long a_lo[4], a_hi[4], b_lo[4], b_hi[4];
#pragma unroll
    for (int m = 0; m < 4; ++m) {
      a_lo[m] = *(const long*)&bufA[aoff[m]];
      a_hi[m] = *(const long*)&bufA[aoff[m] + 32];
    }
#pragma unroll
    for (int j = 0; j < 4; ++j) {
      b_lo[j] = *(const long*)&bufB[boff[j]];
      b_hi[j] = *(const long*)&bufB[boff[j] + 32];
    }

    __builtin_amdgcn_s_setprio(1);
#pragma unroll
    for (int m = 0; m < 4; ++m)
#pragma unroll
      for (int j = 0; j < 4; ++j) {
        acc[m][j] = __builtin_amdgcn_mfma_f32_16x16x32_fp8_fp8(a_lo[m], b_lo[j], acc[m][j], 0, 0, 0);
        acc[m][j] = __builtin_amdgcn_mfma_f32_16x16x32_fp8_fp8(a_hi[m], b_hi[j], acc[m][j], 0, 0, 0);
      }
    __builtin_amdgcn_s_setprio(0);
  }

  // ---- epilogue: e = exp2(dot); masked accumulate; per-m folded ----
  int labc[4];
#pragma unroll
  for (int j = 0; j < 4; ++j) labc[j] = labels[colb + wc * 64 + j * 16 + lr];

  float* redSa = redS;          // [2][64]
  float* redSp = redS + 128;    // [2][64]
#pragma unroll
  for (int m = 0; m < 4; ++m) {
    const int4 lab4 = *(const int4*)&labL[wr * 64 + m * 16 + lhi * 4];
    float asum[4] = {0.f, 0.f, 0.f, 0.f};
    float psum[4] = {0.f, 0.f, 0.f, 0.f};
#pragma unroll
    for (int j = 0; j < 4; ++j) {
      float e0 = exp2f(acc[m][j][0]);
      float e1 = exp2f(acc[m][j][1]);
      float e2 = exp2f(acc[m][j][2]);
      float e3 = exp2f(acc[m][j][3]);
      asum[0] += e0; asum[1] += e1; asum[2] += e2; asum[3] += e3;
      if (lab4.x == labc[j]) psum[0] += e0;
      if (lab4.y == labc[j]) psum[1] += e1;
      if (lab4.z == labc[j]) psum[2] += e2;
      if (lab4.w == labc[j]) psum[3] += e3;
    }
#pragma unroll
    for (int msk = 1; msk <= 8; msk <<= 1)
#pragma unroll
      for (int r = 0; r < 4; ++r) {
        asum[r] += __shfl_xor(asum[r], msk);
        psum[r] += __shfl_xor(psum[r], msk);
      }
    if (wc == 1 && lr == 0) {
#pragma unroll
      for (int r = 0; r < 4; ++r) {
        redSa[wr * 64 + m * 16 + lhi * 4 + r] = asum[r];
        redSp[wr * 64 + m * 16 + lhi * 4 + r] = psum[r];
      }
    }
    if (wc == 0) {
#pragma unroll
      for (int r = 0; r < 4; ++r) { acc[m][0][r] = asum[r]; acc[m][1][r] = psum[r]; }
    }
  }
  EBAR;
  if (wc == 0 && lr == 0) {
#pragma unroll
    for (int m = 0; m < 4; ++m)
#pragma unroll
      for (int r = 0; r < 4; ++r) {
        int idx = m * 16 + lhi * 4 + r;
        float a = acc[m][0][r] + redSa[wr * 64 + idx];
        float p = acc[m][1][r] + redSp[wr * 64 + idx];
        int row = rowbase + wr * 64 + idx;
        part_all[(size_t)colgrp * N + row] = a;
        part_pos[(size_t)colgrp * N + row] = p;
      }
  }
}

// Stage 1: one row per thread, coalesced over cs; per-block tree reduce.
__global__ __launch_bounds__(256) void row_reduce(
    const float* __restrict__ part_pos, const float* __restrict__ part_all,
    float* __restrict__ blocksum) {
  const int i = blockIdx.x * 256 + threadIdx.x;
  float a = 0.f, p = 0.f;
#pragma unroll 4
  for (int cs = 0; cs < CGROUPS; ++cs) {
    a += part_all[(size_t)cs * N + i];
    p += part_pos[(size_t)cs * N + i];
  }
  float s = logf(a) - logf(p);
  __shared__ float red[256];
  red[threadIdx.x] = s;
  __syncthreads();
  for (int off = 128; off > 0; off >>= 1) {
    if (threadIdx.x < off) red[threadIdx.x] += red[threadIdx.x + off];
    __syncthreads();
  }
  if (threadIdx.x == 0) blocksum[blockIdx.x] = red[0];
}

__global__ __launch_bounds__(64) void final_sum(
    const float* __restrict__ blocksum, float* __restrict__ out) {
  float s = (threadIdx.x < N / 256) ? blocksum[threadIdx.x] : 0.f;
#pragma unroll
  for (int m = 1; m <= 32; m <<= 1) s += __shfl_xor(s, m);
  if (threadIdx.x == 0) out[0] = s / (float)N;
}

extern "C" void kernel_launch(void* const* d_in, const int* in_sizes, int n_in,
                              void* d_out, int out_size, void* d_ws, size_t ws_size,
                              hipStream_t stream) {
  const float* out0   = (const float*)d_in[0];
  const float* out1   = (const float*)d_in[1];
  const int*   labels = (const int*)d_in[2];
  float*       out    = (float*)d_out;

  char* ws = (char*)d_ws;
  unsigned char* n0 = (unsigned char*)ws;                            // 4 MB
  unsigned char* n1 = (unsigned char*)(ws + (size_t)N * D);          // 4 MB
  float* part_pos = (float*)(ws + (size_t)2 * N * D);                // 2 MB
  float* part_all = part_pos + (size_t)CGROUPS * N;                  // 2 MB
  float* blocksum = part_all + (size_t)CGROUPS * N;                  // 128 B

  hipLaunchKernelGGL(normalize_kernel, dim3(2 * N / 4), dim3(256), 0, stream,
                     out0, out1, n0, n1);
  hipLaunchKernelGGL(ntxent_main, dim3(4096), dim3(256), 0, stream,
                     n0, n1, labels, part_pos, part_all);
  hipLaunchKernelGGL(row_reduce, dim3(N / 256), dim3(256), 0, stream,
                     part_pos, part_all, blocksum);
  hipLaunchKernelGGL(final_sum, dim3(1), dim3(64), 0, stream,
                     blocksum, out);
}

// Round 14
// 107.448 us; speedup vs baseline: 1.7763x; 1.7763x over previous
//
#include <hip/hip_runtime.h>

using f32x4 = __attribute__((ext_vector_type(4))) float;
using long2v = __attribute__((ext_vector_type(2))) long;

constexpr int   N = 8192;
constexpr int   D = 512;
// sqrt((1/T) * log2(e)) folded into the normalized vectors; dot feeds exp2 directly.
constexpr float SCALE_FOLD = 1.6986436f;
constexpr int   CGROUPS = 64;                        // 64 col groups of 128

static __device__ __forceinline__ void gld16(const unsigned char* g, unsigned char* l) {
  __builtin_amdgcn_global_load_lds(
      (const __attribute__((address_space(1))) void*)g,
      (__attribute__((address_space(3))) void*)l, 16, 0, 0);
}

// One wave per row; rows [0,N) -> out0, [N,2N) -> out1.  f32 -> fp8 e4m3 (OCP).
// Global layout per row is PRE-PERMUTED for the GEMM's LDS scheme:
//   64B k-tile T, logical 8B slot k8 (=4h+g) stored at granule (g ^ ((row>>1)&3)),
//   half h.  So GEMM staging is plain-linear gld16 and the b128 LDS read at
//   ksl = lhi ^ ((lr>>1)&3) delivers k8={lhi, lhi+4} — R11's 0-conflict pattern.
__global__ __launch_bounds__(256) void normalize_kernel(
    const float* __restrict__ in0, const float* __restrict__ in1,
    unsigned char* __restrict__ n0, unsigned char* __restrict__ n1) {
  int gw   = (blockIdx.x * 256 + threadIdx.x) >> 6;
  int lane = threadIdx.x & 63;
  int row  = (gw < N) ? gw : gw - N;
  const float* src = (gw < N) ? in0 + (size_t)row * D : in1 + (size_t)row * D;
  unsigned char* dstrow = (gw < N) ? n0 + (size_t)row * D : n1 + (size_t)row * D;

  const float4* s4 = reinterpret_cast<const float4*>(src) + (size_t)lane * 2;
  float4 v0 = s4[0], v1 = s4[1];
  float ss = v0.x*v0.x + v0.y*v0.y + v0.z*v0.z + v0.w*v0.w
           + v1.x*v1.x + v1.y*v1.y + v1.z*v1.z + v1.w*v1.w;
#pragma unroll
  for (int m = 1; m <= 32; m <<= 1) ss += __shfl_xor(ss, m);
  float s = SCALE_FOLD / fmaxf(sqrtf(ss), 1e-12f);

  int w0 = 0, w1 = 0;
  w0 = __builtin_amdgcn_cvt_pk_fp8_f32(v0.x * s, v0.y * s, w0, false);
  w0 = __builtin_amdgcn_cvt_pk_fp8_f32(v0.z * s, v0.w * s, w0, true);
  w1 = __builtin_amdgcn_cvt_pk_fp8_f32(v1.x * s, v1.y * s, w1, false);
  w1 = __builtin_amdgcn_cvt_pk_fp8_f32(v1.z * s, v1.w * s, w1, true);
  int2 o; o.x = w0; o.y = w1;

  const int c  = (row >> 1) & 3;
  const int k8 = lane & 7;                 // logical 8B slot in the 64B k-tile
  const int g  = k8 & 3, h = k8 >> 2;
  const int off = (lane >> 3) * 64 + ((g ^ c) * 16) + h * 8;
  *reinterpret_cast<int2*>(dstrow + off) = o;
}

// fp8 fused GEMM: 128x128 tile, 4 waves, BK=64 (8 K-steps), 3-deep circular LDS
// (48 KiB), counted vmcnt(4) gates. Per step: 8 ds_read_b128 vs 32 MFMA.
// LDS byte-addressing identical to the measured-0-conflict bf16 layout.
__global__ __launch_bounds__(256) void ntxent_main(
    const unsigned char* __restrict__ n0, const unsigned char* __restrict__ n1,
    const int* __restrict__ labels,
    float* __restrict__ part_pos, float* __restrict__ part_all) {
  __shared__ unsigned char As[3][128 * 64];   // 24 KiB
  __shared__ unsigned char Bs[3][128 * 64];   // 24 KiB
  __shared__ float redS[256];                 // 1 KiB
  __shared__ int   labL[128];                 // 0.5 KiB

  const int t    = threadIdx.x;
  const int lane = t & 63;
  const int wid  = t >> 6;
  const int lr   = lane & 15;
  const int lhi  = lane >> 4;
  const int wr   = wid >> 1;   // 0/1 : rows wr*64..+64
  const int wc   = wid & 1;    // 0/1 : cols wc*64..+64

  // Bijective XCD swizzle (grid = 4096, %8==0)
  const int swz = (blockIdx.x & 7) * 512 + (blockIdx.x >> 3);
  const int rowtile = swz >> 6;        // 0..63
  const int colgrp  = swz & 63;        // 0..63
  const int rowbase = rowtile * 128;
  const int colb    = colgrp * 128;

  if (t < 128) labL[t] = labels[rowbase + t];

  // ---- staging (plain linear; global is pre-permuted by normalize) ----
  const unsigned char* gA = n0 + (size_t)(rowbase + (t >> 2)) * D + (t & 3) * 16;
  const unsigned char* gB = n1 + (size_t)(colb    + (t >> 2)) * D + (t & 3) * 16;
  unsigned char* const lA = &As[0][0] + (t >> 2) * 64 + (t & 3) * 16;
  unsigned char* const lB = &Bs[0][0] + (t >> 2) * 64 + (t & 3) * 16;

#define STAGE(st, sb) do { \
    const unsigned char* _ga = gA + (st) * 64; \
    const unsigned char* _gb = gB + (st) * 64; \
    unsigned char* _la = lA + (sb) * 8192; \
    unsigned char* _lb = lB + (sb) * 8192; \
    gld16(_ga, _la); gld16(_ga + (size_t)64 * D, _la + 4096); \
    gld16(_gb, _lb); gld16(_gb + (size_t)64 * D, _lb + 4096); \
  } while (0)

  // ---- ds_read byte offsets (proven 0-conflict pattern) ----
  const int ksl = lhi ^ ((lr >> 1) & 3);
  int aoff[4];
#pragma unroll
  for (int m = 0; m < 4; ++m) aoff[m] = (wr * 64 + m * 16 + lr) * 64 + ksl * 16;
  int boff[4];
#pragma unroll
  for (int j = 0; j < 4; ++j) boff[j] = (wc * 64 + j * 16 + lr) * 64 + ksl * 16;

#define GATE4 asm volatile("s_waitcnt vmcnt(4)\n\ts_barrier" ::: "memory")
#define GATE0 asm volatile("s_waitcnt vmcnt(0)\n\ts_barrier" ::: "memory")
#define EBAR  asm volatile("s_waitcnt lgkmcnt(0)\n\ts_barrier" ::: "memory")

  f32x4 acc[4][4];
#pragma unroll
  for (int m = 0; m < 4; ++m)
#pragma unroll
    for (int j = 0; j < 4; ++j) acc[m][j] = (f32x4){0.f, 0.f, 0.f, 0.f};

  // prologue: stage k-tiles 0,1 into bufs 0,1  (8 loads outstanding)
  STAGE(0, 0);
  STAGE(1, 1);

#pragma unroll
  for (int kk = 0; kk < 8; ++kk) {
    // drain own oldest k-tile's 4 loads; keep next tile's 4 in flight
    if (kk < 7) { GATE4; } else { GATE0; }

    // stage k-tile kk+2 into buf (kk+2)%3 (readers finished at step kk-1)
    if (kk < 6) STAGE(kk + 2, (kk + 2) % 3);

    const unsigned char* bufA = &As[kk % 3][0];
    const unsigned char* bufB = &Bs[kk % 3][0];
    long2v a[4], b[4];
#pragma unroll
    for (int m = 0; m < 4; ++m) a[m] = *(const long2v*)&bufA[aoff[m]];
#pragma unroll
    for (int j = 0; j < 4; ++j) b[j] = *(const long2v*)&bufB[boff[j]];

    __builtin_amdgcn_s_setprio(1);
#pragma unroll
    for (int m = 0; m < 4; ++m)
#pragma unroll
      for (int j = 0; j < 4; ++j) {
        acc[m][j] = __builtin_amdgcn_mfma_f32_16x16x32_fp8_fp8(a[m][0], b[j][0], acc[m][j], 0, 0, 0);
        acc[m][j] = __builtin_amdgcn_mfma_f32_16x16x32_fp8_fp8(a[m][1], b[j][1], acc[m][j], 0, 0, 0);
      }
    __builtin_amdgcn_s_setprio(0);
  }

  // ---- epilogue: e = exp2(dot); masked accumulate; per-m folded ----
  int labc[4];
#pragma unroll
  for (int j = 0; j < 4; ++j) labc[j] = labels[colb + wc * 64 + j * 16 + lr];

  float* redSa = redS;          // [2][64]
  float* redSp = redS + 128;    // [2][64]
#pragma unroll
  for (int m = 0; m < 4; ++m) {
    const int4 lab4 = *(const int4*)&labL[wr * 64 + m * 16 + lhi * 4];
    float asum[4] = {0.f, 0.f, 0.f, 0.f};
    float psum[4] = {0.f, 0.f, 0.f, 0.f};
#pragma unroll
    for (int j = 0; j < 4; ++j) {
      float e0 = exp2f(acc[m][j][0]);
      float e1 = exp2f(acc[m][j][1]);
      float e2 = exp2f(acc[m][j][2]);
      float e3 = exp2f(acc[m][j][3]);
      asum[0] += e0; asum[1] += e1; asum[2] += e2; asum[3] += e3;
      if (lab4.x == labc[j]) psum[0] += e0;
      if (lab4.y == labc[j]) psum[1] += e1;
      if (lab4.z == labc[j]) psum[2] += e2;
      if (lab4.w == labc[j]) psum[3] += e3;
    }
#pragma unroll
    for (int msk = 1; msk <= 8; msk <<= 1)
#pragma unroll
      for (int r = 0; r < 4; ++r) {
        asum[r] += __shfl_xor(asum[r], msk);
        psum[r] += __shfl_xor(psum[r], msk);
      }
    if (wc == 1 && lr == 0) {
#pragma unroll
      for (int r = 0; r < 4; ++r) {
        redSa[wr * 64 + m * 16 + lhi * 4 + r] = asum[r];
        redSp[wr * 64 + m * 16 + lhi * 4 + r] = psum[r];
      }
    }
    if (wc == 0) {
#pragma unroll
      for (int r = 0; r < 4; ++r) { acc[m][0][r] = asum[r]; acc[m][1][r] = psum[r]; }
    }
  }
  EBAR;
  if (wc == 0 && lr == 0) {
#pragma unroll
    for (int m = 0; m < 4; ++m)
#pragma unroll
      for (int r = 0; r < 4; ++r) {
        int idx = m * 16 + lhi * 4 + r;
        float a = acc[m][0][r] + redSa[wr * 64 + idx];
        float p = acc[m][1][r] + redSp[wr * 64 + idx];
        int row = rowbase + wr * 64 + idx;
        part_all[(size_t)colgrp * N + row] = a;
        part_pos[(size_t)colgrp * N + row] = p;
      }
  }
}

// Stage 1: one row per thread, coalesced over cs; per-block tree reduce.
__global__ __launch_bounds__(256) void row_reduce(
    const float* __restrict__ part_pos, const float* __restrict__ part_all,
    float* __restrict__ blocksum) {
  const int i = blockIdx.x * 256 + threadIdx.x;
  float a = 0.f, p = 0.f;
#pragma unroll 4
  for (int cs = 0; cs < CGROUPS; ++cs) {
    a += part_all[(size_t)cs * N + i];
    p += part_pos[(size_t)cs * N + i];
  }
  float s = logf(a) - logf(p);
  __shared__ float red[256];
  red[threadIdx.x] = s;
  __syncthreads();
  for (int off = 128; off > 0; off >>= 1) {
    if (threadIdx.x < off) red[threadIdx.x] += red[threadIdx.x + off];
    __syncthreads();
  }
  if (threadIdx.x == 0) blocksum[blockIdx.x] = red[0];
}

__global__ __launch_bounds__(64) void final_sum(
    const float* __restrict__ blocksum, float* __restrict__ out) {
  float s = (threadIdx.x < N / 256) ? blocksum[threadIdx.x] : 0.f;
#pragma unroll
  for (int m = 1; m <= 32; m <<= 1) s += __shfl_xor(s, m);
  if (threadIdx.x == 0) out[0] = s / (float)N;
}

extern "C" void kernel_launch(void* const* d_in, const int* in_sizes, int n_in,
                              void* d_out, int out_size, void* d_ws, size_t ws_size,
                              hipStream_t stream) {
  const float* out0   = (const float*)d_in[0];
  const float* out1   = (const float*)d_in[1];
  const int*   labels = (const int*)d_in[2];
  float*       out    = (float*)d_out;

  char* ws = (char*)d_ws;
  unsigned char* n0 = (unsigned char*)ws;                            // 4 MB
  unsigned char* n1 = (unsigned char*)(ws + (size_t)N * D);          // 4 MB
  float* part_pos = (float*)(ws + (size_t)2 * N * D);                // 2 MB
  float* part_all = part_pos + (size_t)CGROUPS * N;                  // 2 MB
  float* blocksum = part_all + (size_t)CGROUPS * N;                  // 128 B

  hipLaunchKernelGGL(normalize_kernel, dim3(2 * N / 4), dim3(256), 0, stream,
                     out0, out1, n0, n1);
  hipLaunchKernelGGL(ntxent_main, dim3(4096), dim3(256), 0, stream,
                     n0, n1, labels, part_pos, part_all);
  hipLaunchKernelGGL(row_reduce, dim3(N / 256), dim3(256), 0, stream,
                     part_pos, part_all, blocksum);
  hipLaunchKernelGGL(final_sum, dim3(1), dim3(64), 0, stream,
                     blocksum, out);
}

// Round 16
// 94.071 us; speedup vs baseline: 2.0289x; 1.1422x over previous
//
#include <hip/hip_runtime.h>

using f32x4 = __attribute__((ext_vector_type(4))) float;
using long2v = __attribute__((ext_vector_type(2))) long;

constexpr int   N = 8192;
constexpr int   D = 512;
// sqrt((1/T) * log2(e)) folded into the normalized vectors; dot feeds exp2 directly.
constexpr float SCALE_FOLD = 1.6986436f;
constexpr int   CGROUPS = 64;                        // 64 col groups of 128

static __device__ __forceinline__ void gld16(const unsigned char* g, unsigned char* l) {
  __builtin_amdgcn_global_load_lds(
      (const __attribute__((address_space(1))) void*)g,
      (__attribute__((address_space(3))) void*)l, 16, 0, 0);
}

// Sum over each 16-lane row group on the VALU via DPP row_ror (hazard-safe:
// update_dpp builtin lets the compiler insert the required DPP wait states).
// row_ror:n ctrl encoding = 0x120 + n.
static __device__ __forceinline__ float dpp_rowsum16(float x) {
  x += __int_as_float(__builtin_amdgcn_update_dpp(0, __float_as_int(x), 0x121, 0xf, 0xf, true));
  x += __int_as_float(__builtin_amdgcn_update_dpp(0, __float_as_int(x), 0x122, 0xf, 0xf, true));
  x += __int_as_float(__builtin_amdgcn_update_dpp(0, __float_as_int(x), 0x124, 0xf, 0xf, true));
  x += __int_as_float(__builtin_amdgcn_update_dpp(0, __float_as_int(x), 0x128, 0xf, 0xf, true));
  return x;
}

// One wave per row; rows [0,N) -> out0, [N,2N) -> out1.  f32 -> fp8 e4m3 (OCP).
// Global layout per row is PRE-PERMUTED for the GEMM's LDS scheme (see R13 note):
// logical 8B slot k8 (=4h+g) stored at granule (g ^ ((row>>1)&3)), half h.
__global__ __launch_bounds__(256) void normalize_kernel(
    const float* __restrict__ in0, const float* __restrict__ in1,
    unsigned char* __restrict__ n0, unsigned char* __restrict__ n1) {
  int gw   = (blockIdx.x * 256 + threadIdx.x) >> 6;
  int lane = threadIdx.x & 63;
  int row  = (gw < N) ? gw : gw - N;
  const float* src = (gw < N) ? in0 + (size_t)row * D : in1 + (size_t)row * D;
  unsigned char* dstrow = (gw < N) ? n0 + (size_t)row * D : n1 + (size_t)row * D;

  const float4* s4 = reinterpret_cast<const float4*>(src) + (size_t)lane * 2;
  float4 v0 = s4[0], v1 = s4[1];
  float ss = v0.x*v0.x + v0.y*v0.y + v0.z*v0.z + v0.w*v0.w
           + v1.x*v1.x + v1.y*v1.y + v1.z*v1.z + v1.w*v1.w;
#pragma unroll
  for (int m = 1; m <= 32; m <<= 1) ss += __shfl_xor(ss, m);
  float s = SCALE_FOLD / fmaxf(sqrtf(ss), 1e-12f);

  int w0 = 0, w1 = 0;
  w0 = __builtin_amdgcn_cvt_pk_fp8_f32(v0.x * s, v0.y * s, w0, false);
  w0 = __builtin_amdgcn_cvt_pk_fp8_f32(v0.z * s, v0.w * s, w0, true);
  w1 = __builtin_amdgcn_cvt_pk_fp8_f32(v1.x * s, v1.y * s, w1, false);
  w1 = __builtin_amdgcn_cvt_pk_fp8_f32(v1.z * s, v1.w * s, w1, true);
  int2 o; o.x = w0; o.y = w1;

  const int c  = (row >> 1) & 3;
  const int k8 = lane & 7;                 // logical 8B slot in the 64B k-tile
  const int g  = k8 & 3, h = k8 >> 2;
  const int off = (lane >> 3) * 64 + ((g ^ c) * 16) + h * 8;
  *reinterpret_cast<int2*>(dstrow + off) = o;
}

// fp8 fused GEMM: 128x128 tile, 4 waves, BK=64 (8 K-steps), 3-deep circular LDS
// (48 KiB), counted vmcnt(4) gates, 0-conflict b128 reads, DPP epilogue reduce.
__global__ __launch_bounds__(256) void ntxent_main(
    const unsigned char* __restrict__ n0, const unsigned char* __restrict__ n1,
    const int* __restrict__ labels,
    float* __restrict__ part_pos, float* __restrict__ part_all) {
  __shared__ unsigned char As[3][128 * 64];   // 24 KiB
  __shared__ unsigned char Bs[3][128 * 64];   // 24 KiB
  __shared__ float redS[256];                 // 1 KiB
  __shared__ int   labL[128];                 // 0.5 KiB

  const int t    = threadIdx.x;
  const int lane = t & 63;
  const int wid  = t >> 6;
  const int lr   = lane & 15;
  const int lhi  = lane >> 4;
  const int wr   = wid >> 1;   // 0/1 : rows wr*64..+64
  const int wc   = wid & 1;    // 0/1 : cols wc*64..+64

  // Bijective XCD swizzle (grid = 4096, %8==0)
  const int swz = (blockIdx.x & 7) * 512 + (blockIdx.x >> 3);
  const int rowtile = swz >> 6;        // 0..63
  const int colgrp  = swz & 63;        // 0..63
  const int rowbase = rowtile * 128;
  const int colb    = colgrp * 128;

  if (t < 128) labL[t] = labels[rowbase + t];

  // ---- staging (plain linear; global is pre-permuted by normalize) ----
  const unsigned char* gA = n0 + (size_t)(rowbase + (t >> 2)) * D + (t & 3) * 16;
  const unsigned char* gB = n1 + (size_t)(colb    + (t >> 2)) * D + (t & 3) * 16;
  unsigned char* const lA = &As[0][0] + (t >> 2) * 64 + (t & 3) * 16;
  unsigned char* const lB = &Bs[0][0] + (t >> 2) * 64 + (t & 3) * 16;

#define STAGE(st, sb) do { \
    const unsigned char* _ga = gA + (st) * 64; \
    const unsigned char* _gb = gB + (st) * 64; \
    unsigned char* _la = lA + (sb) * 8192; \
    unsigned char* _lb = lB + (sb) * 8192; \
    gld16(_ga, _la); gld16(_ga + (size_t)64 * D, _la + 4096); \
    gld16(_gb, _lb); gld16(_gb + (size_t)64 * D, _lb + 4096); \
  } while (0)

  // ---- ds_read byte offsets (proven 0-conflict pattern) ----
  const int ksl = lhi ^ ((lr >> 1) & 3);
  int aoff[4];
#pragma unroll
  for (int m = 0; m < 4; ++m) aoff[m] = (wr * 64 + m * 16 + lr) * 64 + ksl * 16;
  int boff[4];
#pragma unroll
  for (int j = 0; j < 4; ++j) boff[j] = (wc * 64 + j * 16 + lr) * 64 + ksl * 16;

#define GATE4 asm volatile("s_waitcnt vmcnt(4)\n\ts_barrier" ::: "memory")
#define GATE0 asm volatile("s_waitcnt vmcnt(0)\n\ts_barrier" ::: "memory")
#define EBAR  asm volatile("s_waitcnt lgkmcnt(0)\n\ts_barrier" ::: "memory")

  f32x4 acc[4][4];
#pragma unroll
  for (int m = 0; m < 4; ++m)
#pragma unroll
    for (int j = 0; j < 4; ++j) acc[m][j] = (f32x4){0.f, 0.f, 0.f, 0.f};

  // prologue: stage k-tiles 0,1 into bufs 0,1  (8 loads outstanding)
  STAGE(0, 0);
  STAGE(1, 1);

#pragma unroll
  for (int kk = 0; kk < 8; ++kk) {
    // drain own oldest k-tile's 4 loads; keep next tile's 4 in flight
    if (kk < 7) { GATE4; } else { GATE0; }

    // stage k-tile kk+2 into buf (kk+2)%3 (readers finished at step kk-1)
    if (kk < 6) STAGE(kk + 2, (kk + 2) % 3);

    const unsigned char* bufA = &As[kk % 3][0];
    const unsigned char* bufB = &Bs[kk % 3][0];
    long2v a[4], b[4];
#pragma unroll
    for (int m = 0; m < 4; ++m) a[m] = *(const long2v*)&bufA[aoff[m]];
#pragma unroll
    for (int j = 0; j < 4; ++j) b[j] = *(const long2v*)&bufB[boff[j]];

    __builtin_amdgcn_s_setprio(1);
#pragma unroll
    for (int m = 0; m < 4; ++m)
#pragma unroll
      for (int j = 0; j < 4; ++j) {
        acc[m][j] = __builtin_amdgcn_mfma_f32_16x16x32_fp8_fp8(a[m][0], b[j][0], acc[m][j], 0, 0, 0);
        acc[m][j] = __builtin_amdgcn_mfma_f32_16x16x32_fp8_fp8(a[m][1], b[j][1], acc[m][j], 0, 0, 0);
      }
    __builtin_amdgcn_s_setprio(0);
  }

  // ---- epilogue: e = exp2(dot); masked accumulate; DPP rowsum (VALU-only) ----
  int labc[4];
#pragma unroll
  for (int j = 0; j < 4; ++j) labc[j] = labels[colb + wc * 64 + j * 16 + lr];

  float* redSa = redS;          // [2][64]
  float* redSp = redS + 128;    // [2][64]
#pragma unroll
  for (int m = 0; m < 4; ++m) {
    const int4 lab4 = *(const int4*)&labL[wr * 64 + m * 16 + lhi * 4];
    float asum[4] = {0.f, 0.f, 0.f, 0.f};
    float psum[4] = {0.f, 0.f, 0.f, 0.f};
#pragma unroll
    for (int j = 0; j < 4; ++j) {
      float e0 = exp2f(acc[m][j][0]);
      float e1 = exp2f(acc[m][j][1]);
      float e2 = exp2f(acc[m][j][2]);
      float e3 = exp2f(acc[m][j][3]);
      asum[0] += e0; asum[1] += e1; asum[2] += e2; asum[3] += e3;
      if (lab4.x == labc[j]) psum[0] += e0;
      if (lab4.y == labc[j]) psum[1] += e1;
      if (lab4.z == labc[j]) psum[2] += e2;
      if (lab4.w == labc[j]) psum[3] += e3;
    }
#pragma unroll
    for (int r = 0; r < 4; ++r) {
      asum[r] = dpp_rowsum16(asum[r]);
      psum[r] = dpp_rowsum16(psum[r]);
    }
    if (wc == 1 && lr == 0) {
#pragma unroll
      for (int r = 0; r < 4; ++r) {
        redSa[wr * 64 + m * 16 + lhi * 4 + r] = asum[r];
        redSp[wr * 64 + m * 16 + lhi * 4 + r] = psum[r];
      }
    }
    if (wc == 0) {
#pragma unroll
      for (int r = 0; r < 4; ++r) { acc[m][0][r] = asum[r]; acc[m][1][r] = psum[r]; }
    }
  }
  EBAR;
  if (wc == 0 && lr == 0) {
#pragma unroll
    for (int m = 0; m < 4; ++m)
#pragma unroll
      for (int r = 0; r < 4; ++r) {
        int idx = m * 16 + lhi * 4 + r;
        float a = acc[m][0][r] + redSa[wr * 64 + idx];
        float p = acc[m][1][r] + redSp[wr * 64 + idx];
        int row = rowbase + wr * 64 + idx;
        part_all[(size_t)colgrp * N + row] = a;
        part_pos[(size_t)colgrp * N + row] = p;
      }
  }
}

// Stage 1: one row per thread, coalesced over cs; per-block tree reduce.
__global__ __launch_bounds__(256) void row_reduce(
    const float* __restrict__ part_pos, const float* __restrict__ part_all,
    float* __restrict__ blocksum) {
  const int i = blockIdx.x * 256 + threadIdx.x;
  float a = 0.f, p = 0.f;
#pragma unroll 4
  for (int cs = 0; cs < CGROUPS; ++cs) {
    a += part_all[(size_t)cs * N + i];
    p += part_pos[(size_t)cs * N + i];
  }
  float s = logf(a) - logf(p);
  __shared__ float red[256];
  red[threadIdx.x] = s;
  __syncthreads();
  for (int off = 128; off > 0; off >>= 1) {
    if (threadIdx.x < off) red[threadIdx.x] += red[threadIdx.x + off];
    __syncthreads();
  }
  if (threadIdx.x == 0) blocksum[blockIdx.x] = red[0];
}

__global__ __launch_bounds__(64) void final_sum(
    const float* __restrict__ blocksum, float* __restrict__ out) {
  float s = (threadIdx.x < N / 256) ? blocksum[threadIdx.x] : 0.f;
#pragma unroll
  for (int m = 1; m <= 32; m <<= 1) s += __shfl_xor(s, m);
  if (threadIdx.x == 0) out[0] = s / (float)N;
}

extern "C" void kernel_launch(void* const* d_in, const int* in_sizes, int n_in,
                              void* d_out, int out_size, void* d_ws, size_t ws_size,
                              hipStream_t stream) {
  const float* out0   = (const float*)d_in[0];
  const float* out1   = (const float*)d_in[1];
  const int*   labels = (const int*)d_in[2];
  float*       out    = (float*)d_out;

  char* ws = (char*)d_ws;
  unsigned char* n0 = (unsigned char*)ws;                            // 4 MB
  unsigned char* n1 = (unsigned char*)(ws + (size_t)N * D);          // 4 MB
  float* part_pos = (float*)(ws + (size_t)2 * N * D);                // 2 MB
  float* part_all = part_pos + (size_t)CGROUPS * N;                  // 2 MB
  float* blocksum = part_all + (size_t)CGROUPS * N;                  // 128 B

  hipLaunchKernelGGL(normalize_kernel, dim3(2 * N / 4), dim3(256), 0, stream,
                     out0, out1, n0, n1);
  hipLaunchKernelGGL(ntxent_main, dim3(4096), dim3(256), 0, stream,
                     n0, n1, labels, part_pos, part_all);
  hipLaunchKernelGGL(row_reduce, dim3(N / 256), dim3(256), 0, stream,
                     part_pos, part_all, blocksum);
  hipLaunchKernelGGL(final_sum, dim3(1), dim3(64), 0, stream,
                     blocksum, out);
}

// Round 17
// 80.786 us; speedup vs baseline: 2.3626x; 1.1645x over previous
//
#include <hip/hip_runtime.h>

using f32x4  = __attribute__((ext_vector_type(4))) float;
using f32x16 = __attribute__((ext_vector_type(16))) float;
using i32x8  = __attribute__((ext_vector_type(8))) int;

constexpr int   N = 8192;
constexpr int   D = 512;
// sqrt((1/T) * log2(e)) folded into the normalized vectors; dot feeds exp2 directly.
constexpr float SCALE_FOLD = 1.6986436f;
constexpr int   CGROUPS = 64;                        // 64 col groups of 128

static __device__ __forceinline__ void gld16(const unsigned char* g, unsigned char* l) {
  __builtin_amdgcn_global_load_lds(
      (const __attribute__((address_space(1))) void*)g,
      (__attribute__((address_space(3))) void*)l, 16, 0, 0);
}

// 32-lane column sum on the VALU: 4x row_ror within 16-lane rows, then
// row_bcast15 folds row0->row1 (lanes 16..31 / 48..63 hold the 32-sum).
static __device__ __forceinline__ float dpp_sum32(float x) {
  x += __int_as_float(__builtin_amdgcn_update_dpp(0, __float_as_int(x), 0x121, 0xf, 0xf, true));
  x += __int_as_float(__builtin_amdgcn_update_dpp(0, __float_as_int(x), 0x122, 0xf, 0xf, true));
  x += __int_as_float(__builtin_amdgcn_update_dpp(0, __float_as_int(x), 0x124, 0xf, 0xf, true));
  x += __int_as_float(__builtin_amdgcn_update_dpp(0, __float_as_int(x), 0x128, 0xf, 0xf, true));
  x += __int_as_float(__builtin_amdgcn_update_dpp(0, __float_as_int(x), 0x142, 0xf, 0xf, true));
  return x;
}

// One wave per row; rows [0,N) -> out0, [N,2N) -> out1.  f32 -> fp8 e4m3 (OCP).
// Per-row pre-permutation for the GEMM LDS scheme: within each 64B k-tile,
// logical 16B granule g (=k8>>1, half h=k8&1) stored at granule g ^ ((row>>1)&3).
__global__ __launch_bounds__(256) void normalize_kernel(
    const float* __restrict__ in0, const float* __restrict__ in1,
    unsigned char* __restrict__ n0, unsigned char* __restrict__ n1) {
  int gw   = (blockIdx.x * 256 + threadIdx.x) >> 6;
  int lane = threadIdx.x & 63;
  int row  = (gw < N) ? gw : gw - N;
  const float* src = (gw < N) ? in0 + (size_t)row * D : in1 + (size_t)row * D;
  unsigned char* dstrow = (gw < N) ? n0 + (size_t)row * D : n1 + (size_t)row * D;

  const float4* s4 = reinterpret_cast<const float4*>(src) + (size_t)lane * 2;
  float4 v0 = s4[0], v1 = s4[1];
  float ss = v0.x*v0.x + v0.y*v0.y + v0.z*v0.z + v0.w*v0.w
           + v1.x*v1.x + v1.y*v1.y + v1.z*v1.z + v1.w*v1.w;
#pragma unroll
  for (int m = 1; m <= 32; m <<= 1) ss += __shfl_xor(ss, m);
  float s = SCALE_FOLD / fmaxf(sqrtf(ss), 1e-12f);

  int w0 = 0, w1 = 0;
  w0 = __builtin_amdgcn_cvt_pk_fp8_f32(v0.x * s, v0.y * s, w0, false);
  w0 = __builtin_amdgcn_cvt_pk_fp8_f32(v0.z * s, v0.w * s, w0, true);
  w1 = __builtin_amdgcn_cvt_pk_fp8_f32(v1.x * s, v1.y * s, w1, false);
  w1 = __builtin_amdgcn_cvt_pk_fp8_f32(v1.z * s, v1.w * s, w1, true);
  int2 o; o.x = w0; o.y = w1;

  const int c  = (row >> 1) & 3;
  const int k8 = lane & 7;                 // logical 8B slot in the 64B k-tile
  const int g  = k8 >> 1, h = k8 & 1;      // 16B granule, 8B half (k-contiguous)
  const int off = (lane >> 3) * 64 + ((g ^ c) * 16) + h * 8;
  *reinterpret_cast<int2*>(dstrow + off) = o;
}

// MX-fp8 fused GEMM: 128x128 tile, 4 waves, BK=64 (8 K-steps), 3-deep circular
// LDS (48 KiB), counted vmcnt(4) gates, 0-conflict b128 reads.
// Per K-step: 8 ds_read_b128 + 4x mfma_scale_f32_32x32x64_f8f6f4 (unit scales).
__global__ __launch_bounds__(256) void ntxent_main(
    const unsigned char* __restrict__ n0, const unsigned char* __restrict__ n1,
    const int* __restrict__ labels,
    float* __restrict__ part_pos, float* __restrict__ part_all) {
  __shared__ unsigned char As[3][128 * 64];   // 24 KiB
  __shared__ unsigned char Bs[3][128 * 64];   // 24 KiB
  __shared__ float redS[256];                 // 1 KiB
  __shared__ int   labL[128];                 // 0.5 KiB

  const int t    = threadIdx.x;
  const int lane = t & 63;
  const int wid  = t >> 6;
  const int l31  = lane & 31;
  const int hi   = lane >> 5;   // k-group of the 32x32 frags; also D-row half
  const int wr   = wid >> 1;    // 0/1 : rows wr*64..+64
  const int wc   = wid & 1;     // 0/1 : cols wc*64..+64

  // Bijective XCD swizzle (grid = 4096, %8==0)
  const int swz = (blockIdx.x & 7) * 512 + (blockIdx.x >> 3);
  const int rowtile = swz >> 6;        // 0..63
  const int colgrp  = swz & 63;        // 0..63
  const int rowbase = rowtile * 128;
  const int colb    = colgrp * 128;

  if (t < 128) labL[t] = labels[rowbase + t];

  // ---- staging (plain linear; global is pre-permuted by normalize) ----
  const unsigned char* gA = n0 + (size_t)(rowbase + (t >> 2)) * D + (t & 3) * 16;
  const unsigned char* gB = n1 + (size_t)(colb    + (t >> 2)) * D + (t & 3) * 16;
  unsigned char* const lA = &As[0][0] + (t >> 2) * 64 + (t & 3) * 16;
  unsigned char* const lB = &Bs[0][0] + (t >> 2) * 64 + (t & 3) * 16;

#define STAGE(st, sb) do { \
    const unsigned char* _ga = gA + (st) * 64; \
    const unsigned char* _gb = gB + (st) * 64; \
    unsigned char* _la = lA + (sb) * 8192; \
    unsigned char* _lb = lB + (sb) * 8192; \
    gld16(_ga, _la); gld16(_ga + (size_t)64 * D, _la + 4096); \
    gld16(_gb, _lb); gld16(_gb + (size_t)64 * D, _lb + 4096); \
  } while (0)

  // ---- ds_read byte offsets: frag row tr, logical granule 2*hi (+1 at ^16) ----
  int aoff[2], boff[2];
#pragma unroll
  for (int mi = 0; mi < 2; ++mi) {
    int tr = wr * 64 + mi * 32 + l31;
    aoff[mi] = tr * 64 + (((hi << 1) ^ ((tr >> 1) & 3)) << 4);
  }
#pragma unroll
  for (int ji = 0; ji < 2; ++ji) {
    int tc = wc * 64 + ji * 32 + l31;
    boff[ji] = tc * 64 + (((hi << 1) ^ ((tc >> 1) & 3)) << 4);
  }

#define GATE4 asm volatile("s_waitcnt vmcnt(4)\n\ts_barrier" ::: "memory")
#define GATE0 asm volatile("s_waitcnt vmcnt(0)\n\ts_barrier" ::: "memory")
#define EBAR  asm volatile("s_waitcnt lgkmcnt(0)\n\ts_barrier" ::: "memory")

  const int sc1 = 0x7f7f7f7f;   // e8m0 scale = 1.0 in all byte lanes

  f32x16 acc[2][2];
#pragma unroll
  for (int mi = 0; mi < 2; ++mi)
#pragma unroll
    for (int ji = 0; ji < 2; ++ji) acc[mi][ji] = 0.f;

  // prologue: stage k-tiles 0,1 into bufs 0,1  (8 loads outstanding)
  STAGE(0, 0);
  STAGE(1, 1);

#pragma unroll
  for (int kk = 0; kk < 8; ++kk) {
    if (kk < 7) { GATE4; } else { GATE0; }
    if (kk < 6) STAGE(kk + 2, (kk + 2) % 3);

    const unsigned char* bufA = &As[kk % 3][0];
    const unsigned char* bufB = &Bs[kk % 3][0];
    i32x8 a[2], b[2];
#pragma unroll
    for (int mi = 0; mi < 2; ++mi) {
      int4 lo = *(const int4*)&bufA[aoff[mi]];
      int4 hh = *(const int4*)&bufA[aoff[mi] ^ 16];
      a[mi] = (i32x8){lo.x, lo.y, lo.z, lo.w, hh.x, hh.y, hh.z, hh.w};
    }
#pragma unroll
    for (int ji = 0; ji < 2; ++ji) {
      int4 lo = *(const int4*)&bufB[boff[ji]];
      int4 hh = *(const int4*)&bufB[boff[ji] ^ 16];
      b[ji] = (i32x8){lo.x, lo.y, lo.z, lo.w, hh.x, hh.y, hh.z, hh.w};
    }

    __builtin_amdgcn_s_setprio(1);
#pragma unroll
    for (int mi = 0; mi < 2; ++mi)
#pragma unroll
      for (int ji = 0; ji < 2; ++ji)
        acc[mi][ji] = __builtin_amdgcn_mfma_scale_f32_32x32x64_f8f6f4(
            a[mi], b[ji], acc[mi][ji], 0, 0, 0, sc1, 0, sc1);
    __builtin_amdgcn_s_setprio(0);
  }

  // ---- epilogue: e = exp2(dot); masked accumulate; DPP 32-lane col-sum ----
  // D layout (32x32): col = lane&31, row = (reg&3) + 8*(reg>>2) + 4*(lane>>5).
  const int labc0 = labels[colb + wc * 64 + l31];
  const int labc1 = labels[colb + wc * 64 + 32 + l31];

  float* redSa = redS;          // [2][64]
  float* redSp = redS + 128;    // [2][64]
  f32x4 keepA[2][4], keepP[2][4];
#pragma unroll
  for (int mi = 0; mi < 2; ++mi) {
#pragma unroll
    for (int rq = 0; rq < 4; ++rq) {
      const int4 lab4 = *(const int4*)&labL[wr * 64 + mi * 32 + rq * 8 + 4 * hi];
      f32x4 at, pt;
#pragma unroll
      for (int rr = 0; rr < 4; ++rr) {
        const int r = rq * 4 + rr;
        float e0 = exp2f(acc[mi][0][r]);
        float e1 = exp2f(acc[mi][1][r]);
        float as = e0 + e1;
        int lb = (rr == 0) ? lab4.x : (rr == 1) ? lab4.y : (rr == 2) ? lab4.z : lab4.w;
        float ps = ((lb == labc0) ? e0 : 0.f) + ((lb == labc1) ? e1 : 0.f);
        at[rr] = dpp_sum32(as);
        pt[rr] = dpp_sum32(ps);
      }
      if (wc == 1 && l31 == 16) {
        *(f32x4*)&redSa[wr * 64 + mi * 32 + rq * 8 + 4 * hi] = at;
        *(f32x4*)&redSp[wr * 64 + mi * 32 + rq * 8 + 4 * hi] = pt;
      }
      keepA[mi][rq] = at;
      keepP[mi][rq] = pt;
    }
  }
  EBAR;
  if (wc == 0 && l31 == 16) {
#pragma unroll
    for (int mi = 0; mi < 2; ++mi)
#pragma unroll
      for (int rq = 0; rq < 4; ++rq) {
        const int idx = wr * 64 + mi * 32 + rq * 8 + 4 * hi;
        f32x4 a4 = keepA[mi][rq];
        f32x4 p4 = keepP[mi][rq];
        const f32x4 ra = *(const f32x4*)&redSa[idx];
        const f32x4 rp = *(const f32x4*)&redSp[idx];
#pragma unroll
        for (int rr = 0; rr < 4; ++rr) { a4[rr] += ra[rr]; p4[rr] += rp[rr]; }
        const int row = rowbase + idx;
        *(f32x4*)&part_all[(size_t)colgrp * N + row] = a4;
        *(f32x4*)&part_pos[(size_t)colgrp * N + row] = p4;
      }
  }
}

// Stage 1: one row per thread, coalesced over cs; per-block tree reduce.
__global__ __launch_bounds__(256) void row_reduce(
    const float* __restrict__ part_pos, const float* __restrict__ part_all,
    float* __restrict__ blocksum) {
  const int i = blockIdx.x * 256 + threadIdx.x;
  float a = 0.f, p = 0.f;
#pragma unroll 4
  for (int cs = 0; cs < CGROUPS; ++cs) {
    a += part_all[(size_t)cs * N + i];
    p += part_pos[(size_t)cs * N + i];
  }
  float s = logf(a) - logf(p);
  __shared__ float red[256];
  red[threadIdx.x] = s;
  __syncthreads();
  for (int off = 128; off > 0; off >>= 1) {
    if (threadIdx.x < off) red[threadIdx.x] += red[threadIdx.x + off];
    __syncthreads();
  }
  if (threadIdx.x == 0) blocksum[blockIdx.x] = red[0];
}

__global__ __launch_bounds__(64) void final_sum(
    const float* __restrict__ blocksum, float* __restrict__ out) {
  float s = (threadIdx.x < N / 256) ? blocksum[threadIdx.x] : 0.f;
#pragma unroll
  for (int m = 1; m <= 32; m <<= 1) s += __shfl_xor(s, m);
  if (threadIdx.x == 0) out[0] = s / (float)N;
}

extern "C" void kernel_launch(void* const* d_in, const int* in_sizes, int n_in,
                              void* d_out, int out_size, void* d_ws, size_t ws_size,
                              hipStream_t stream) {
  const float* out0   = (const float*)d_in[0];
  const float* out1   = (const float*)d_in[1];
  const int*   labels = (const int*)d_in[2];
  float*       out    = (float*)d_out;

  char* ws = (char*)d_ws;
  unsigned char* n0 = (unsigned char*)ws;                            // 4 MB
  unsigned char* n1 = (unsigned char*)(ws + (size_t)N * D);          // 4 MB
  float* part_pos = (float*)(ws + (size_t)2 * N * D);                // 2 MB
  float* part_all = part_pos + (size_t)CGROUPS * N;                  // 2 MB
  float* blocksum = part_all + (size_t)CGROUPS * N;                  // 128 B

  hipLaunchKernelGGL(normalize_kernel, dim3(2 * N / 4), dim3(256), 0, stream,
                     out0, out1, n0, n1);
  hipLaunchKernelGGL(ntxent_main, dim3(4096), dim3(256), 0, stream,
                     n0, n1, labels, part_pos, part_all);
  hipLaunchKernelGGL(row_reduce, dim3(N / 256), dim3(256), 0, stream,
                     part_pos, part_all, blocksum);
  hipLaunchKernelGGL(final_sum, dim3(1), dim3(64), 0, stream,
                     blocksum, out);
}

// Round 19
// 70.775 us; speedup vs baseline: 2.6967x; 1.1414x over previous
//
#include <hip/hip_runtime.h>

using f32x4  = __attribute__((ext_vector_type(4))) float;
using f32x16 = __attribute__((ext_vector_type(16))) float;
using i32x8  = __attribute__((ext_vector_type(8))) int;

constexpr int   N = 8192;
constexpr int   D = 512;
// sqrt((1/T) * log2(e)) folded into the normalized vectors; dot feeds exp2 directly.
constexpr float SCALE_FOLD = 1.6986436f;
constexpr int   CGROUPS = 64;                        // 64 col groups of 128

static __device__ __forceinline__ void gld16(const unsigned char* g, unsigned char* l) {
  __builtin_amdgcn_global_load_lds(
      (const __attribute__((address_space(1))) void*)g,
      (__attribute__((address_space(3))) void*)l, 16, 0, 0);
}

// One wave per row; rows [0,N) -> out0, [N,2N) -> out1.  f32 -> fp8 e4m3 (OCP).
// Per-row pre-permutation for the GEMM LDS scheme: within each 64B k-tile,
// logical 16B granule g (=k8>>1, half h=k8&1) stored at granule g ^ ((row>>1)&3).
__global__ __launch_bounds__(256) void normalize_kernel(
    const float* __restrict__ in0, const float* __restrict__ in1,
    unsigned char* __restrict__ n0, unsigned char* __restrict__ n1) {
  int gw   = (blockIdx.x * 256 + threadIdx.x) >> 6;
  int lane = threadIdx.x & 63;
  int row  = (gw < N) ? gw : gw - N;
  const float* src = (gw < N) ? in0 + (size_t)row * D : in1 + (size_t)row * D;
  unsigned char* dstrow = (gw < N) ? n0 + (size_t)row * D : n1 + (size_t)row * D;

  const float4* s4 = reinterpret_cast<const float4*>(src) + (size_t)lane * 2;
  float4 v0 = s4[0], v1 = s4[1];
  float ss = v0.x*v0.x + v0.y*v0.y + v0.z*v0.z + v0.w*v0.w
           + v1.x*v1.x + v1.y*v1.y + v1.z*v1.z + v1.w*v1.w;
#pragma unroll
  for (int m = 1; m <= 32; m <<= 1) ss += __shfl_xor(ss, m);
  float s = SCALE_FOLD / fmaxf(sqrtf(ss), 1e-12f);

  int w0 = 0, w1 = 0;
  w0 = __builtin_amdgcn_cvt_pk_fp8_f32(v0.x * s, v0.y * s, w0, false);
  w0 = __builtin_amdgcn_cvt_pk_fp8_f32(v0.z * s, v0.w * s, w0, true);
  w1 = __builtin_amdgcn_cvt_pk_fp8_f32(v1.x * s, v1.y * s, w1, false);
  w1 = __builtin_amdgcn_cvt_pk_fp8_f32(v1.z * s, v1.w * s, w1, true);
  int2 o; o.x = w0; o.y = w1;

  const int c  = (row >> 1) & 3;
  const int k8 = lane & 7;                 // logical 8B slot in the 64B k-tile
  const int g  = k8 >> 1, h = k8 & 1;      // 16B granule, 8B half (k-contiguous)
  const int off = (lane >> 3) * 64 + ((g ^ c) * 16) + h * 8;
  *reinterpret_cast<int2*>(dstrow + off) = o;
}

// MX-fp8 fused GEMM: 128x128 tile, 4 waves, BK=64 (8 K-steps), 3-deep circular
// LDS (48 KiB), counted vmcnt(4) gates. SWAPPED operands: mfma(b, a) gives
// D[j][i] with lane = output ROW i, regs = cols j -> row-reduction is
// in-register + one shfl_xor(32).
__global__ __launch_bounds__(256) void ntxent_main(
    const unsigned char* __restrict__ n0, const unsigned char* __restrict__ n1,
    const int* __restrict__ labels,
    float* __restrict__ part_pos, float* __restrict__ part_all) {
  __shared__ unsigned char As[3][128 * 64];   // 24 KiB
  __shared__ unsigned char Bs[3][128 * 64];   // 24 KiB
  __shared__ float redS[256];                 // 1 KiB
  __shared__ int   labC[128];                 // 0.5 KiB: col labels of this colgrp

  const int t    = threadIdx.x;
  const int lane = t & 63;
  const int wid  = t >> 6;
  const int l31  = lane & 31;
  const int hi   = lane >> 5;   // k-half of frags; col-half of D regs
  const int wr   = wid >> 1;    // 0/1 : rows wr*64..+64
  const int wc   = wid & 1;     // 0/1 : cols wc*64..+64

  // Bijective XCD swizzle (grid = 4096, %8==0)
  const int swz = (blockIdx.x & 7) * 512 + (blockIdx.x >> 3);
  const int rowtile = swz >> 6;        // 0..63
  const int colgrp  = swz & 63;        // 0..63
  const int rowbase = rowtile * 128;
  const int colb    = colgrp * 128;

  if (t < 128) labC[t] = labels[colb + t];

  // ---- staging (plain linear; global is pre-permuted by normalize) ----
  const unsigned char* gA = n0 + (size_t)(rowbase + (t >> 2)) * D + (t & 3) * 16;
  const unsigned char* gB = n1 + (size_t)(colb    + (t >> 2)) * D + (t & 3) * 16;
  unsigned char* const lA = &As[0][0] + (t >> 2) * 64 + (t & 3) * 16;
  unsigned char* const lB = &Bs[0][0] + (t >> 2) * 64 + (t & 3) * 16;

#define STAGE(st, sb) do { \
    const unsigned char* _ga = gA + (st) * 64; \
    const unsigned char* _gb = gB + (st) * 64; \
    unsigned char* _la = lA + (sb) * 8192; \
    unsigned char* _lb = lB + (sb) * 8192; \
    gld16(_ga, _la); gld16(_ga + (size_t)64 * D, _la + 4096); \
    gld16(_gb, _lb); gld16(_gb + (size_t)64 * D, _lb + 4096); \
  } while (0)

  // ---- ds_read byte offsets: frag row tr, logical granule 2*hi (+1 at ^16) ----
  int aoff[2], boff[2];
#pragma unroll
  for (int mi = 0; mi < 2; ++mi) {
    int tr = wr * 64 + mi * 32 + l31;
    aoff[mi] = tr * 64 + (((hi << 1) ^ ((tr >> 1) & 3)) << 4);
  }
#pragma unroll
  for (int ji = 0; ji < 2; ++ji) {
    int tc = wc * 64 + ji * 32 + l31;
    boff[ji] = tc * 64 + (((hi << 1) ^ ((tc >> 1) & 3)) << 4);
  }

#define GATE4 asm volatile("s_waitcnt vmcnt(4)\n\ts_barrier" ::: "memory")
#define GATE0 asm volatile("s_waitcnt vmcnt(0)\n\ts_barrier" ::: "memory")
#define EBAR  asm volatile("s_waitcnt lgkmcnt(0)\n\ts_barrier" ::: "memory")

  const int sc1 = 0x7f7f7f7f;   // e8m0 scale = 1.0 in all byte lanes

  f32x16 acc[2][2];             // acc[ji][mi]: lane=row i, regs=col j
#pragma unroll
  for (int ji = 0; ji < 2; ++ji)
#pragma unroll
    for (int mi = 0; mi < 2; ++mi) acc[ji][mi] = 0.f;

  // prologue: stage k-tiles 0,1 into bufs 0,1  (8 loads outstanding)
  STAGE(0, 0);
  STAGE(1, 1);

#pragma unroll
  for (int kk = 0; kk < 8; ++kk) {
    if (kk < 7) { GATE4; } else { GATE0; }
    if (kk < 6) STAGE(kk + 2, (kk + 2) % 3);

    const unsigned char* bufA = &As[kk % 3][0];
    const unsigned char* bufB = &Bs[kk % 3][0];
    i32x8 a[2], b[2];
#pragma unroll
    for (int mi = 0; mi < 2; ++mi) {
      int4 lo = *(const int4*)&bufA[aoff[mi]];
      int4 hh = *(const int4*)&bufA[aoff[mi] ^ 16];
      a[mi] = (i32x8){lo.x, lo.y, lo.z, lo.w, hh.x, hh.y, hh.z, hh.w};
    }
#pragma unroll
    for (int ji = 0; ji < 2; ++ji) {
      int4 lo = *(const int4*)&bufB[boff[ji]];
      int4 hh = *(const int4*)&bufB[boff[ji] ^ 16];
      b[ji] = (i32x8){lo.x, lo.y, lo.z, lo.w, hh.x, hh.y, hh.z, hh.w};
    }

    __builtin_amdgcn_s_setprio(1);
#pragma unroll
    for (int ji = 0; ji < 2; ++ji)
#pragma unroll
      for (int mi = 0; mi < 2; ++mi)
        acc[ji][mi] = __builtin_amdgcn_mfma_scale_f32_32x32x64_f8f6f4(
            b[ji], a[mi], acc[ji][mi], 0, 0, 0, sc1, 0, sc1);
    __builtin_amdgcn_s_setprio(0);
  }

  // ---- epilogue: lane-local row reduction ----
  // D[j][i]: lane l31 = row i (within mi-frag), reg r -> col
  // j = wc*64 + ji*32 + (r&3) + 8*(r>>2) + 4*hi.
  int labi[2];
#pragma unroll
  for (int mi = 0; mi < 2; ++mi)
    labi[mi] = labels[rowbase + wr * 64 + mi * 32 + l31];

  float asum[2] = {0.f, 0.f};
  float psum[2] = {0.f, 0.f};
#pragma unroll
  for (int ji = 0; ji < 2; ++ji)
#pragma unroll
    for (int rq = 0; rq < 4; ++rq) {
      const int4 labj = *(const int4*)&labC[wc * 64 + ji * 32 + rq * 8 + 4 * hi];
#pragma unroll
      for (int mi = 0; mi < 2; ++mi)
#pragma unroll
        for (int rr = 0; rr < 4; ++rr) {
          float e = exp2f(acc[ji][mi][rq * 4 + rr]);
          asum[mi] += e;
          int lb = (rr == 0) ? labj.x : (rr == 1) ? labj.y : (rr == 2) ? labj.z : labj.w;
          if (lb == labi[mi]) psum[mi] += e;
        }
    }

  // fold the two col-halves (lane l <-> l+32 hold same row, different cols)
#pragma unroll
  for (int mi = 0; mi < 2; ++mi) {
    asum[mi] += __shfl_xor(asum[mi], 32);
    psum[mi] += __shfl_xor(psum[mi], 32);
  }

  // cross-wave combine over wc
  float* redSa = redS;          // [128]
  float* redSp = redS + 128;    // [128]
  if (wc == 1 && hi == 0) {
#pragma unroll
    for (int mi = 0; mi < 2; ++mi) {
      redSa[wr * 64 + mi * 32 + l31] = asum[mi];
      redSp[wr * 64 + mi * 32 + l31] = psum[mi];
    }
  }
  EBAR;
  if (wc == 0 && hi == 0) {
#pragma unroll
    for (int mi = 0; mi < 2; ++mi) {
      const int idx = wr * 64 + mi * 32 + l31;
      const int row = rowbase + idx;
      part_all[(size_t)colgrp * N + row] = asum[mi] + redSa[idx];
      part_pos[(size_t)colgrp * N + row] = psum[mi] + redSp[idx];
    }
  }
}

// Stage 1: one row per thread, coalesced over cs; per-block tree reduce.
__global__ __launch_bounds__(256) void row_reduce(
    const float* __restrict__ part_pos, const float* __restrict__ part_all,
    float* __restrict__ blocksum) {
  const int i = blockIdx.x * 256 + threadIdx.x;
  float a = 0.f, p = 0.f;
#pragma unroll 4
  for (int cs = 0; cs < CGROUPS; ++cs) {
    a += part_all[(size_t)cs * N + i];
    p += part_pos[(size_t)cs * N + i];
  }
  float s = logf(a) - logf(p);
  __shared__ float red[256];
  red[threadIdx.x] = s;
  __syncthreads();
  for (int off = 128; off > 0; off >>= 1) {
    if (threadIdx.x < off) red[threadIdx.x] += red[threadIdx.x + off];
    __syncthreads();
  }
  if (threadIdx.x == 0) blocksum[blockIdx.x] = red[0];
}

__global__ __launch_bounds__(64) void final_sum(
    const float* __restrict__ blocksum, float* __restrict__ out) {
  float s = (threadIdx.x < N / 256) ? blocksum[threadIdx.x] : 0.f;
#pragma unroll
  for (int m = 1; m <= 32; m <<= 1) s += __shfl_xor(s, m);
  if (threadIdx.x == 0) out[0] = s / (float)N;
}

extern "C" void kernel_launch(void* const* d_in, const int* in_sizes, int n_in,
                              void* d_out, int out_size, void* d_ws, size_t ws_size,
                              hipStream_t stream) {
  const float* out0   = (const float*)d_in[0];
  const float* out1   = (const float*)d_in[1];
  const int*   labels = (const int*)d_in[2];
  float*       out    = (float*)d_out;

  char* ws = (char*)d_ws;
  unsigned char* n0 = (unsigned char*)ws;                            // 4 MB
  unsigned char* n1 = (unsigned char*)(ws + (size_t)N * D);          // 4 MB
  float* part_pos = (float*)(ws + (size_t)2 * N * D);                // 2 MB
  float* part_all = part_pos + (size_t)CGROUPS * N;                  // 2 MB
  float* blocksum = part_all + (size_t)CGROUPS * N;                  // 128 B

  hipLaunchKernelGGL(normalize_kernel, dim3(2 * N / 4), dim3(256), 0, stream,
                     out0, out1, n0, n1);
  hipLaunchKernelGGL(ntxent_main, dim3(4096), dim3(256), 0, stream,
                     n0, n1, labels, part_pos, part_all);
  hipLaunchKernelGGL(row_reduce, dim3(N / 256), dim3(256), 0, stream,
                     part_pos, part_all, blocksum);
  hipLaunchKernelGGL(final_sum, dim3(1), dim3(64), 0, stream,
                     blocksum, out);
}

// Round 20
// 66.751 us; speedup vs baseline: 2.8593x; 1.0603x over previous
//
#include <hip/hip_runtime.h>

using f32x4  = __attribute__((ext_vector_type(4))) float;
using f32x16 = __attribute__((ext_vector_type(16))) float;
using i32x8  = __attribute__((ext_vector_type(8))) int;

constexpr int   N = 8192;
constexpr int   D = 512;
// sqrt((1/T) * log2(e)) folded into the normalized vectors; dot feeds exp2 directly.
constexpr float SCALE_FOLD = 1.6986436f;
constexpr int   CGROUPS = 64;                        // 64 col groups of 128

static __device__ __forceinline__ void gld16(const unsigned char* g, unsigned char* l) {
  __builtin_amdgcn_global_load_lds(
      (const __attribute__((address_space(1))) void*)g,
      (__attribute__((address_space(3))) void*)l, 16, 0, 0);
}

// One wave per row; rows [0,N) -> out0, [N,2N) -> out1.  f32 -> fp8 e4m3 (OCP).
// Per-row pre-permutation for the GEMM LDS scheme: within each 64B k-tile,
// logical 16B granule g (=k8>>1, half h=k8&1) stored at granule g ^ ((row>>1)&3).
__global__ __launch_bounds__(256) void normalize_kernel(
    const float* __restrict__ in0, const float* __restrict__ in1,
    unsigned char* __restrict__ n0, unsigned char* __restrict__ n1) {
  int gw   = (blockIdx.x * 256 + threadIdx.x) >> 6;
  int lane = threadIdx.x & 63;
  int row  = (gw < N) ? gw : gw - N;
  const float* src = (gw < N) ? in0 + (size_t)row * D : in1 + (size_t)row * D;
  unsigned char* dstrow = (gw < N) ? n0 + (size_t)row * D : n1 + (size_t)row * D;

  const float4* s4 = reinterpret_cast<const float4*>(src) + (size_t)lane * 2;
  float4 v0 = s4[0], v1 = s4[1];
  float ss = v0.x*v0.x + v0.y*v0.y + v0.z*v0.z + v0.w*v0.w
           + v1.x*v1.x + v1.y*v1.y + v1.z*v1.z + v1.w*v1.w;
#pragma unroll
  for (int m = 1; m <= 32; m <<= 1) ss += __shfl_xor(ss, m);
  float s = SCALE_FOLD / fmaxf(sqrtf(ss), 1e-12f);

  int w0 = 0, w1 = 0;
  w0 = __builtin_amdgcn_cvt_pk_fp8_f32(v0.x * s, v0.y * s, w0, false);
  w0 = __builtin_amdgcn_cvt_pk_fp8_f32(v0.z * s, v0.w * s, w0, true);
  w1 = __builtin_amdgcn_cvt_pk_fp8_f32(v1.x * s, v1.y * s, w1, false);
  w1 = __builtin_amdgcn_cvt_pk_fp8_f32(v1.z * s, v1.w * s, w1, true);
  int2 o; o.x = w0; o.y = w1;

  const int c  = (row >> 1) & 3;
  const int k8 = lane & 7;                 // logical 8B slot in the 64B k-tile
  const int g  = k8 >> 1, h = k8 & 1;      // 16B granule, 8B half (k-contiguous)
  const int off = (lane >> 3) * 64 + ((g ^ c) * 16) + h * 8;
  *reinterpret_cast<int2*>(dstrow + off) = o;
}

// MX-fp8 fused GEMM: 128x128 tile, 4 waves, BK=64 (8 K-steps), 2-deep LDS
// (32 KiB -> 4 blocks/CU with the reg cap), counted vmcnt(4) gates; tile kk+2
// staged into buf kk&1 AFTER a post-MFMA barrier (all waves' reads done).
// SWAPPED operands: mfma(b, a) -> lane = output row, regs = cols.
__global__ __launch_bounds__(256, 4) void ntxent_main(
    const unsigned char* __restrict__ n0, const unsigned char* __restrict__ n1,
    const int* __restrict__ labels,
    float* __restrict__ part_pos, float* __restrict__ part_all) {
  __shared__ unsigned char As[2][128 * 64];   // 16 KiB
  __shared__ unsigned char Bs[2][128 * 64];   // 16 KiB
  __shared__ float redS[256];                 // 1 KiB
  __shared__ int   labC[128];                 // 0.5 KiB: col labels of this colgrp

  const int t    = threadIdx.x;
  const int lane = t & 63;
  const int wid  = t >> 6;
  const int l31  = lane & 31;
  const int hi   = lane >> 5;   // k-half of frags; col-half of D regs
  const int wr   = wid >> 1;    // 0/1 : rows wr*64..+64
  const int wc   = wid & 1;     // 0/1 : cols wc*64..+64

  // Bijective XCD swizzle (grid = 4096, %8==0)
  const int swz = (blockIdx.x & 7) * 512 + (blockIdx.x >> 3);
  const int rowtile = swz >> 6;        // 0..63
  const int colgrp  = swz & 63;        // 0..63
  const int rowbase = rowtile * 128;
  const int colb    = colgrp * 128;

  if (t < 128) labC[t] = labels[colb + t];

  // ---- staging (plain linear; global is pre-permuted by normalize) ----
  const unsigned char* gA = n0 + (size_t)(rowbase + (t >> 2)) * D + (t & 3) * 16;
  const unsigned char* gB = n1 + (size_t)(colb    + (t >> 2)) * D + (t & 3) * 16;
  unsigned char* const lA = &As[0][0] + (t >> 2) * 64 + (t & 3) * 16;
  unsigned char* const lB = &Bs[0][0] + (t >> 2) * 64 + (t & 3) * 16;

#define STAGE(st, sb) do { \
    const unsigned char* _ga = gA + (st) * 64; \
    const unsigned char* _gb = gB + (st) * 64; \
    unsigned char* _la = lA + (sb) * 8192; \
    unsigned char* _lb = lB + (sb) * 8192; \
    gld16(_ga, _la); gld16(_ga + (size_t)64 * D, _la + 4096); \
    gld16(_gb, _lb); gld16(_gb + (size_t)64 * D, _lb + 4096); \
  } while (0)

  // ---- ds_read byte offsets: frag row tr, logical granule 2*hi (+1 at ^16) ----
  int aoff[2], boff[2];
#pragma unroll
  for (int mi = 0; mi < 2; ++mi) {
    int tr = wr * 64 + mi * 32 + l31;
    aoff[mi] = tr * 64 + (((hi << 1) ^ ((tr >> 1) & 3)) << 4);
  }
#pragma unroll
  for (int ji = 0; ji < 2; ++ji) {
    int tc = wc * 64 + ji * 32 + l31;
    boff[ji] = tc * 64 + (((hi << 1) ^ ((tc >> 1) & 3)) << 4);
  }

#define GATE4 asm volatile("s_waitcnt vmcnt(4)\n\ts_barrier" ::: "memory")
#define GATE0 asm volatile("s_waitcnt vmcnt(0)\n\ts_barrier" ::: "memory")
#define BARP  asm volatile("s_barrier" ::: "memory")
#define EBAR  asm volatile("s_waitcnt lgkmcnt(0)\n\ts_barrier" ::: "memory")

  const int sc1 = 0x7f7f7f7f;   // e8m0 scale = 1.0 in all byte lanes

  f32x16 acc[2][2];             // acc[ji][mi]: lane=row i, regs=col j
#pragma unroll
  for (int ji = 0; ji < 2; ++ji)
#pragma unroll
    for (int mi = 0; mi < 2; ++mi) acc[ji][mi] = 0.f;

  // prologue: stage k-tiles 0,1 into bufs 0,1  (8 loads outstanding)
  STAGE(0, 0);
  STAGE(1, 1);

#pragma unroll
  for (int kk = 0; kk < 8; ++kk) {
    // drain own oldest k-tile's 4 loads; keep next tile's 4 in flight
    if (kk < 7) { GATE4; } else { GATE0; }

    const unsigned char* bufA = &As[kk & 1][0];
    const unsigned char* bufB = &Bs[kk & 1][0];
    i32x8 a[2], b[2];
#pragma unroll
    for (int mi = 0; mi < 2; ++mi) {
      int4 lo = *(const int4*)&bufA[aoff[mi]];
      int4 hh = *(const int4*)&bufA[aoff[mi] ^ 16];
      a[mi] = (i32x8){lo.x, lo.y, lo.z, lo.w, hh.x, hh.y, hh.z, hh.w};
    }
#pragma unroll
    for (int ji = 0; ji < 2; ++ji) {
      int4 lo = *(const int4*)&bufB[boff[ji]];
      int4 hh = *(const int4*)&bufB[boff[ji] ^ 16];
      b[ji] = (i32x8){lo.x, lo.y, lo.z, lo.w, hh.x, hh.y, hh.z, hh.w};
    }

    __builtin_amdgcn_s_setprio(1);
#pragma unroll
    for (int ji = 0; ji < 2; ++ji)
#pragma unroll
      for (int mi = 0; mi < 2; ++mi)
        acc[ji][mi] = __builtin_amdgcn_mfma_scale_f32_32x32x64_f8f6f4(
            b[ji], a[mi], acc[ji][mi], 0, 0, 0, sc1, 0, sc1);
    __builtin_amdgcn_s_setprio(0);

    // After this barrier every wave has finished reading buf kk&1
    // (compiler-inserted lgkmcnt before MFMA) -> safe to overwrite it.
    if (kk < 6) { BARP; STAGE(kk + 2, kk & 1); }
  }

  // ---- epilogue: lane-local row reduction ----
  // D[j][i]: lane l31 = row i (within mi-frag), reg r -> col
  // j = wc*64 + ji*32 + (r&3) + 8*(r>>2) + 4*hi.
  int labi[2];
#pragma unroll
  for (int mi = 0; mi < 2; ++mi)
    labi[mi] = labels[rowbase + wr * 64 + mi * 32 + l31];

  float asum[2] = {0.f, 0.f};
  float psum[2] = {0.f, 0.f};
#pragma unroll
  for (int ji = 0; ji < 2; ++ji)
#pragma unroll
    for (int rq = 0; rq < 4; ++rq) {
      const int4 labj = *(const int4*)&labC[wc * 64 + ji * 32 + rq * 8 + 4 * hi];
#pragma unroll
      for (int mi = 0; mi < 2; ++mi)
#pragma unroll
        for (int rr = 0; rr < 4; ++rr) {
          float e = exp2f(acc[ji][mi][rq * 4 + rr]);
          asum[mi] += e;
          int lb = (rr == 0) ? labj.x : (rr == 1) ? labj.y : (rr == 2) ? labj.z : labj.w;
          if (lb == labi[mi]) psum[mi] += e;
        }
    }

  // fold the two col-halves (lane l <-> l+32 hold same row, different cols)
#pragma unroll
  for (int mi = 0; mi < 2; ++mi) {
    asum[mi] += __shfl_xor(asum[mi], 32);
    psum[mi] += __shfl_xor(psum[mi], 32);
  }

  // cross-wave combine over wc
  float* redSa = redS;          // [128]
  float* redSp = redS + 128;    // [128]
  if (wc == 1 && hi == 0) {
#pragma unroll
    for (int mi = 0; mi < 2; ++mi) {
      redSa[wr * 64 + mi * 32 + l31] = asum[mi];
      redSp[wr * 64 + mi * 32 + l31] = psum[mi];
    }
  }
  EBAR;
  if (wc == 0 && hi == 0) {
#pragma unroll
    for (int mi = 0; mi < 2; ++mi) {
      const int idx = wr * 64 + mi * 32 + l31;
      const int row = rowbase + idx;
      part_all[(size_t)colgrp * N + row] = asum[mi] + redSa[idx];
      part_pos[(size_t)colgrp * N + row] = psum[mi] + redSp[idx];
    }
  }
}

// Stage 1: one row per thread, coalesced over cs; per-block tree reduce.
__global__ __launch_bounds__(256) void row_reduce(
    const float* __restrict__ part_pos, const float* __restrict__ part_all,
    float* __restrict__ blocksum) {
  const int i = blockIdx.x * 256 + threadIdx.x;
  float a = 0.f, p = 0.f;
#pragma unroll 4
  for (int cs = 0; cs < CGROUPS; ++cs) {
    a += part_all[(size_t)cs * N + i];
    p += part_pos[(size_t)cs * N + i];
  }
  float s = logf(a) - logf(p);
  __shared__ float red[256];
  red[threadIdx.x] = s;
  __syncthreads();
  for (int off = 128; off > 0; off >>= 1) {
    if (threadIdx.x < off) red[threadIdx.x] += red[threadIdx.x + off];
    __syncthreads();
  }
  if (threadIdx.x == 0) blocksum[blockIdx.x] = red[0];
}

__global__ __launch_bounds__(64) void final_sum(
    const float* __restrict__ blocksum, float* __restrict__ out) {
  float s = (threadIdx.x < N / 256) ? blocksum[threadIdx.x] : 0.f;
#pragma unroll
  for (int m = 1; m <= 32; m <<= 1) s += __shfl_xor(s, m);
  if (threadIdx.x == 0) out[0] = s / (float)N;
}

extern "C" void kernel_launch(void* const* d_in, const int* in_sizes, int n_in,
                              void* d_out, int out_size, void* d_ws, size_t ws_size,
                              hipStream_t stream) {
  const float* out0   = (const float*)d_in[0];
  const float* out1   = (const float*)d_in[1];
  const int*   labels = (const int*)d_in[2];
  float*       out    = (float*)d_out;

  char* ws = (char*)d_ws;
  unsigned char* n0 = (unsigned char*)ws;                            // 4 MB
  unsigned char* n1 = (unsigned char*)(ws + (size_t)N * D);          // 4 MB
  float* part_pos = (float*)(ws + (size_t)2 * N * D);                // 2 MB
  float* part_all = part_pos + (size_t)CGROUPS * N;                  // 2 MB
  float* blocksum = part_all + (size_t)CGROUPS * N;                  // 128 B

  hipLaunchKernelGGL(normalize_kernel, dim3(2 * N / 4), dim3(256), 0, stream,
                     out0, out1, n0, n1);
  hipLaunchKernelGGL(ntxent_main, dim3(4096), dim3(256), 0, stream,
                     n0, n1, labels, part_pos, part_all);
  hipLaunchKernelGGL(row_reduce, dim3(N / 256), dim3(256), 0, stream,
                     part_pos, part_all, blocksum);
  hipLaunchKernelGGL(final_sum, dim3(1), dim3(64), 0, stream,
                     blocksum, out);
}